// Round 1
// baseline (128.504 us; speedup 1.0000x reference)
//
#include <hip/hip_runtime.h>
#include <stdint.h>

#define NW        16777216   // OUT_F*IN_F
#define NPACKED   8388608
#define NGROUPS   131072
#define NOUT      167772
#define M_ROWS    1024
#define K_DIM     4096
#define N_DIM     4096

typedef __attribute__((ext_vector_type(8))) __bf16 bf16x8;
typedef __attribute__((ext_vector_type(4))) float f32x4;
typedef __attribute__((ext_vector_type(8))) unsigned short ushort8;

__device__ __forceinline__ unsigned short f2bf(float f) {
    union { float f; unsigned int u; } v; v.f = f;
    unsigned int r = v.u + 0x7fffu + ((v.u >> 16) & 1u);
    return (unsigned short)(r >> 16);
}

__device__ __forceinline__ void gload_lds16(const void* g, void* l) {
    __builtin_amdgcn_global_load_lds(
        (__attribute__((address_space(1))) void*)(uintptr_t)g,
        (__attribute__((address_space(3))) void*)(uint32_t)(uintptr_t)l,
        16, 0, 0);
}

// ---- x fp32 -> bf16, 8 elems/thread ----
__global__ void k_convert_x(const float* __restrict__ x, unsigned short* __restrict__ xb) {
    int t = blockIdx.x * 256 + threadIdx.x;          // 524288 threads
    const float4* xv = (const float4*)x;
    float4 a = xv[2 * t], b = xv[2 * t + 1];
    ushort8 o;
    o[0] = f2bf(a.x); o[1] = f2bf(a.y); o[2] = f2bf(a.z); o[3] = f2bf(a.w);
    o[4] = f2bf(b.x); o[5] = f2bf(b.y); o[6] = f2bf(b.z); o[7] = f2bf(b.w);
    *(ushort8*)(xb + 8 * (size_t)t) = o;
}

// ---- group dequant: 4 packed ints -> 8 bf16 weights per thread ----
__global__ void k_dequant(const int* __restrict__ packed, const float* __restrict__ scales,
                          const float* __restrict__ offsets, unsigned short* __restrict__ Wb) {
    int t = blockIdx.x * 256 + threadIdx.x;          // 2097152 threads
    int4 p = ((const int4*)packed)[t];
    int g = t >> 4;                                   // 8 weights/thread, 128/group
    float s = scales[g], o = offsets[g];
    ushort8 r;
    r[0] = f2bf((float)(p.x & 15) * s + o); r[1] = f2bf((float)((p.x >> 4) & 15) * s + o);
    r[2] = f2bf((float)(p.y & 15) * s + o); r[3] = f2bf((float)((p.y >> 4) & 15) * s + o);
    r[4] = f2bf((float)(p.z & 15) * s + o); r[5] = f2bf((float)((p.z >> 4) & 15) * s + o);
    r[6] = f2bf((float)(p.w & 15) * s + o); r[7] = f2bf((float)((p.w >> 4) & 15) * s + o);
    *(ushort8*)(Wb + 8 * (size_t)t) = r;
}

// ---- outlier scatter, last-write-wins via priority atomicMax ----
__global__ void k_out1(const int* __restrict__ idx, int* __restrict__ maxk, int n) {
    int t = blockIdx.x * 256 + threadIdx.x;
    if (t < n) atomicMax(&maxk[idx[t]], t + 1);
}
__global__ void k_out2(const int* __restrict__ idx, const float* __restrict__ val,
                       const int* __restrict__ maxk, unsigned short* __restrict__ Wb, int n) {
    int t = blockIdx.x * 256 + threadIdx.x;
    if (t < n) {
        int i = idx[t];
        if (maxk[i] == t + 1) Wb[i] = f2bf(val[t]);
    }
}

// ---- bf16 GEMM: C[M,N] = A[M,K] * B[N,K]^T + bias, m97-style 128x128 tile ----
__global__ __launch_bounds__(256, 1)
void k_gemm(const unsigned short* __restrict__ A, const unsigned short* __restrict__ B,
            const float* __restrict__ bias, float* __restrict__ C) {
    __shared__ unsigned short sA[128 * 64];   // 16 KB
    __shared__ unsigned short sB[128 * 64];   // 16 KB

    const int bn = blockIdx.x, bm = blockIdx.y;
    const int tid = threadIdx.x;
    const int wave = tid >> 6, lane = tid & 63;
    const int wr = wave >> 1, wc = wave & 1;           // 2x2 wave grid, 64x64 each
    const int l15 = lane & 15, l4 = lane >> 4;

    f32x4 acc[4][4] = {};

    // per-thread staging geometry: chunk = wave*4+c covers 1024B = 8 rows of the tile
    for (int kt = 0; kt < K_DIM / 64; ++kt) {
#pragma unroll
        for (int c = 0; c < 4; ++c) {
            int chunk = wave * 4 + c;                  // 0..15
            int o = chunk * 1024 + lane * 16;          // byte offset in tile
            int row = o >> 7;                          // /128 (64 bf16 per row)
            int colb = o & 127;
            const unsigned short* ga = A + (size_t)(bm * 128 + row) * K_DIM + kt * 64 + (colb >> 1);
            const unsigned short* gb = B + (size_t)(bn * 128 + row) * K_DIM + kt * 64 + (colb >> 1);
            gload_lds16(ga, (char*)sA + chunk * 1024);
            gload_lds16(gb, (char*)sB + chunk * 1024);
        }
        asm volatile("s_waitcnt vmcnt(0)" ::: "memory");
        __syncthreads();
#pragma unroll
        for (int kk = 0; kk < 2; ++kk) {
            bf16x8 af[4], bfr[4];
            int kbyte = kk * 64 + l4 * 16;
#pragma unroll
            for (int m = 0; m < 4; ++m)
                af[m] = *(const bf16x8*)((const char*)sA + (wr * 64 + m * 16 + l15) * 128 + kbyte);
#pragma unroll
            for (int n = 0; n < 4; ++n)
                bfr[n] = *(const bf16x8*)((const char*)sB + (wc * 64 + n * 16 + l15) * 128 + kbyte);
#pragma unroll
            for (int m = 0; m < 4; ++m)
#pragma unroll
                for (int n = 0; n < 4; ++n)
                    acc[m][n] = __builtin_amdgcn_mfma_f32_16x16x32_bf16(af[m], bfr[n], acc[m][n], 0, 0, 0);
        }
        __syncthreads();
    }

    // epilogue: D row = l4*4 + r, col = l15 within each 16x16 fragment
#pragma unroll
    for (int m = 0; m < 4; ++m) {
#pragma unroll
        for (int n = 0; n < 4; ++n) {
            int gn = bn * 128 + wc * 64 + n * 16 + l15;
            float bv = bias[gn];
#pragma unroll
            for (int r = 0; r < 4; ++r) {
                int gm = bm * 128 + wr * 64 + m * 16 + l4 * 4 + r;
                C[(size_t)gm * N_DIM + gn] = acc[m][n][r] + bv;
            }
        }
    }
}

extern "C" void kernel_launch(void* const* d_in, const int* in_sizes, int n_in,
                              void* d_out, int out_size, void* d_ws, size_t ws_size,
                              hipStream_t stream) {
    const float* x       = (const float*)d_in[0];
    const int*   packed  = (const int*)d_in[1];
    const float* scales  = (const float*)d_in[2];
    const float* offsets = (const float*)d_in[3];
    const int*   oidx    = (const int*)d_in[4];
    const float* oval    = (const float*)d_in[5];
    const float* bias    = (const float*)d_in[6];
    float* out = (float*)d_out;

    char* ws = (char*)d_ws;
    unsigned short* xb   = (unsigned short*)ws;                                   // 8 MB
    unsigned short* Wb   = (unsigned short*)(ws + (size_t)8 * 1024 * 1024);       // 32 MB
    int*            maxk = (int*)(ws + (size_t)40 * 1024 * 1024);                 // 64 MB

    hipMemsetAsync(maxk, 0, (size_t)NW * 4, stream);
    k_convert_x<<<524288 / 256, 256, 0, stream>>>(x, xb);
    k_dequant<<<2097152 / 256, 256, 0, stream>>>(packed, scales, offsets, Wb);
    k_out1<<<(NOUT + 255) / 256, 256, 0, stream>>>(oidx, maxk, NOUT);
    k_out2<<<(NOUT + 255) / 256, 256, 0, stream>>>(oidx, oval, maxk, Wb, NOUT);
    k_gemm<<<dim3(N_DIM / 128, M_ROWS / 128), 256, 0, stream>>>(xb, Wb, bias, out);
}

// Round 2
// 104.758 us; speedup vs baseline: 1.2267x; 1.2267x over previous
//
#include <hip/hip_runtime.h>
#include <stdint.h>

#define NW        16777216   // OUT_F*IN_F
#define NOUT      167772
#define M_ROWS    1024
#define K_DIM     4096
#define N_DIM     4096
#define SPLITK    4
#define KSTEPS    (K_DIM / 64 / SPLITK)   // 16 K-steps of 64 per split

typedef __attribute__((ext_vector_type(8))) __bf16 bf16x8;
typedef __attribute__((ext_vector_type(4))) float f32x4;
typedef __attribute__((ext_vector_type(8))) unsigned short ushort8;

__device__ __forceinline__ unsigned short f2bf(float f) {
    union { float f; unsigned int u; } v; v.f = f;
    unsigned int r = v.u + 0x7fffu + ((v.u >> 16) & 1u);
    return (unsigned short)(r >> 16);
}

__device__ __forceinline__ void gload_lds16(const void* g, void* l) {
    __builtin_amdgcn_global_load_lds(
        (__attribute__((address_space(1))) void*)(uintptr_t)g,
        (__attribute__((address_space(3))) void*)(uint32_t)(uintptr_t)l,
        16, 0, 0);
}

// ---- x fp32 -> bf16, 8 elems/thread ----
__global__ void k_convert_x(const float* __restrict__ x, unsigned short* __restrict__ xb) {
    int t = blockIdx.x * 256 + threadIdx.x;          // 524288 threads
    const float4* xv = (const float4*)x;
    float4 a = xv[2 * t], b = xv[2 * t + 1];
    ushort8 o;
    o[0] = f2bf(a.x); o[1] = f2bf(a.y); o[2] = f2bf(a.z); o[3] = f2bf(a.w);
    o[4] = f2bf(b.x); o[5] = f2bf(b.y); o[6] = f2bf(b.z); o[7] = f2bf(b.w);
    *(ushort8*)(xb + 8 * (size_t)t) = o;
}

// ---- group dequant: 4 packed ints -> 8 bf16 weights per thread ----
__global__ void k_dequant(const int* __restrict__ packed, const float* __restrict__ scales,
                          const float* __restrict__ offsets, unsigned short* __restrict__ Wb) {
    int t = blockIdx.x * 256 + threadIdx.x;          // 2097152 threads
    int4 p = ((const int4*)packed)[t];
    int g = t >> 4;                                   // 8 weights/thread, 128/group
    float s = scales[g], o = offsets[g];
    ushort8 r;
    r[0] = f2bf((float)(p.x & 15) * s + o); r[1] = f2bf((float)((p.x >> 4) & 15) * s + o);
    r[2] = f2bf((float)(p.y & 15) * s + o); r[3] = f2bf((float)((p.y >> 4) & 15) * s + o);
    r[4] = f2bf((float)(p.z & 15) * s + o); r[5] = f2bf((float)((p.z >> 4) & 15) * s + o);
    r[6] = f2bf((float)(p.w & 15) * s + o); r[7] = f2bf((float)((p.w >> 4) & 15) * s + o);
    *(ushort8*)(Wb + 8 * (size_t)t) = r;
}

// ---- outlier scatter, last-write-wins via priority atomicMax ----
// k_out0 zeroes only the used slots (maxk aliases the partial buffer, so it
// holds garbage from the previous call — untouched slots are never read).
__global__ void k_out0(const int* __restrict__ idx, int* __restrict__ maxk, int n) {
    int t = blockIdx.x * 256 + threadIdx.x;
    if (t < n) maxk[idx[t]] = 0;
}
__global__ void k_out1(const int* __restrict__ idx, int* __restrict__ maxk, int n) {
    int t = blockIdx.x * 256 + threadIdx.x;
    if (t < n) atomicMax(&maxk[idx[t]], t + 1);
}
__global__ void k_out2(const int* __restrict__ idx, const float* __restrict__ val,
                       const int* __restrict__ maxk, unsigned short* __restrict__ Wb, int n) {
    int t = blockIdx.x * 256 + threadIdx.x;
    if (t < n) {
        int i = idx[t];
        if (maxk[i] == t + 1) Wb[i] = f2bf(val[t]);
    }
}

// ---- bf16 GEMM with split-K: P[ks] += A[M, Kslice] * B[N, Kslice]^T ----
__global__ __launch_bounds__(256)
void k_gemm(const unsigned short* __restrict__ A, const unsigned short* __restrict__ B,
            float* __restrict__ P) {
    __shared__ unsigned short sA[128 * 64];   // 16 KB
    __shared__ unsigned short sB[128 * 64];   // 16 KB

    const int bn = blockIdx.x, bm = blockIdx.y, ks = blockIdx.z;
    const int tid = threadIdx.x;
    const int wave = tid >> 6, lane = tid & 63;
    const int wr = wave >> 1, wc = wave & 1;           // 2x2 wave grid, 64x64 each
    const int l15 = lane & 15, l4 = lane >> 4;

    f32x4 acc[4][4] = {};

    for (int kt = ks * KSTEPS; kt < ks * KSTEPS + KSTEPS; ++kt) {
#pragma unroll
        for (int c = 0; c < 4; ++c) {
            int chunk = wave * 4 + c;                  // 0..15
            int o = chunk * 1024 + lane * 16;          // byte offset in tile
            int row = o >> 7;                          // /128 (64 bf16 per row)
            int colb = o & 127;
            const unsigned short* ga = A + (size_t)(bm * 128 + row) * K_DIM + kt * 64 + (colb >> 1);
            const unsigned short* gb = B + (size_t)(bn * 128 + row) * K_DIM + kt * 64 + (colb >> 1);
            gload_lds16(ga, (char*)sA + chunk * 1024);
            gload_lds16(gb, (char*)sB + chunk * 1024);
        }
        asm volatile("s_waitcnt vmcnt(0)" ::: "memory");
        __syncthreads();
#pragma unroll
        for (int kk = 0; kk < 2; ++kk) {
            bf16x8 af[4], bfr[4];
            int kbyte = kk * 64 + l4 * 16;
#pragma unroll
            for (int m = 0; m < 4; ++m)
                af[m] = *(const bf16x8*)((const char*)sA + (wr * 64 + m * 16 + l15) * 128 + kbyte);
#pragma unroll
            for (int n = 0; n < 4; ++n)
                bfr[n] = *(const bf16x8*)((const char*)sB + (wc * 64 + n * 16 + l15) * 128 + kbyte);
#pragma unroll
            for (int m = 0; m < 4; ++m)
#pragma unroll
                for (int n = 0; n < 4; ++n)
                    acc[m][n] = __builtin_amdgcn_mfma_f32_16x16x32_bf16(af[m], bfr[n], acc[m][n], 0, 0, 0);
        }
        __syncthreads();
    }

    float* Pk = P + (size_t)ks * NW;
#pragma unroll
    for (int m = 0; m < 4; ++m) {
#pragma unroll
        for (int n = 0; n < 4; ++n) {
            int gn = bn * 128 + wc * 64 + n * 16 + l15;
#pragma unroll
            for (int r = 0; r < 4; ++r) {
                int gm = bm * 128 + wr * 64 + m * 16 + l4 * 4 + r;
                Pk[(size_t)gm * N_DIM + gn] = acc[m][n][r];
            }
        }
    }
}

// ---- reduce 4 partials + bias, float4 ----
__global__ void k_reduce(const float* __restrict__ P, const float* __restrict__ bias,
                         float* __restrict__ out) {
    int t = blockIdx.x * 256 + threadIdx.x;           // 1,048,576 threads
    const float4* p0 = (const float4*)P;
    const float4* p1 = (const float4*)(P + (size_t)NW);
    const float4* p2 = (const float4*)(P + (size_t)2 * NW);
    const float4* p3 = (const float4*)(P + (size_t)3 * NW);
    float4 a = p0[t], b = p1[t], c = p2[t], d = p3[t];
    float4 bv = ((const float4*)bias)[t & (N_DIM / 4 - 1)];
    float4 r;
    r.x = a.x + b.x + c.x + d.x + bv.x;
    r.y = a.y + b.y + c.y + d.y + bv.y;
    r.z = a.z + b.z + c.z + d.z + bv.z;
    r.w = a.w + b.w + c.w + d.w + bv.w;
    ((float4*)out)[t] = r;
}

extern "C" void kernel_launch(void* const* d_in, const int* in_sizes, int n_in,
                              void* d_out, int out_size, void* d_ws, size_t ws_size,
                              hipStream_t stream) {
    const float* x       = (const float*)d_in[0];
    const int*   packed  = (const int*)d_in[1];
    const float* scales  = (const float*)d_in[2];
    const float* offsets = (const float*)d_in[3];
    const int*   oidx    = (const int*)d_in[4];
    const float* oval    = (const float*)d_in[5];
    const float* bias    = (const float*)d_in[6];
    float* out = (float*)d_out;

    char* ws = (char*)d_ws;
    unsigned short* xb = (unsigned short*)ws;                                   // 8 MB
    unsigned short* Wb = (unsigned short*)(ws + (size_t)8 * 1024 * 1024);       // 32 MB
    float*          P  = (float*)(ws + (size_t)40 * 1024 * 1024);               // 64 MB (SPLITK partials)
    int*          maxk = (int*)P;   // aliases P: used only before the GEMM in stream order

    k_convert_x<<<524288 / 256, 256, 0, stream>>>(x, xb);
    k_dequant<<<2097152 / 256, 256, 0, stream>>>(packed, scales, offsets, Wb);
    k_out0<<<(NOUT + 255) / 256, 256, 0, stream>>>(oidx, maxk, NOUT);
    k_out1<<<(NOUT + 255) / 256, 256, 0, stream>>>(oidx, maxk, NOUT);
    k_out2<<<(NOUT + 255) / 256, 256, 0, stream>>>(oidx, oval, maxk, Wb, NOUT);
    k_gemm<<<dim3(N_DIM / 128, M_ROWS / 128, SPLITK), 256, 0, stream>>>(xb, Wb, P);
    k_reduce<<<(out_size / 4 + 255) / 256, 256, 0, stream>>>(P, bias, out);
}

// Round 3
// 82.921 us; speedup vs baseline: 1.5497x; 1.2633x over previous
//
#include <hip/hip_runtime.h>
#include <stdint.h>

#define NW        16777216   // OUT_F*IN_F (weight count)
#define NOUT      167772
#define M_ROWS    1024
#define K_DIM     4096
#define N_DIM     4096
#define SPLITK    4
#define KT_PER    (K_DIM / 64 / SPLITK)       // 16 K-tiles (BK=64) per split
#define PSZ       (M_ROWS * N_DIM)            // 4,194,304 elems per partial

typedef __attribute__((ext_vector_type(8))) __bf16 bf16x8;
typedef __attribute__((ext_vector_type(4))) float f32x4;
typedef __attribute__((ext_vector_type(8))) unsigned short ushort8;

__device__ __forceinline__ unsigned short f2bf(float f) {
    union { float f; unsigned int u; } v; v.f = f;
    unsigned int r = v.u + 0x7fffu + ((v.u >> 16) & 1u);
    return (unsigned short)(r >> 16);
}
__device__ __forceinline__ float bf2f(unsigned short u) {
    union { unsigned int u; float f; } v; v.u = ((unsigned int)u) << 16;
    return v.f;
}
__device__ __forceinline__ void gload_lds16(const void* g, void* l) {
    __builtin_amdgcn_global_load_lds(
        (__attribute__((address_space(1))) void*)(uintptr_t)g,
        (__attribute__((address_space(3))) void*)(uint32_t)(uintptr_t)l,
        16, 0, 0);
}
#define MFMA16(a, b, c) __builtin_amdgcn_mfma_f32_16x16x32_bf16((a), (b), (c), 0, 0, 0)

// ---- fused: x fp32->bf16 + weight group dequant ----
__global__ void k_prep(const float* __restrict__ x, const int* __restrict__ packed,
                       const float* __restrict__ scales, const float* __restrict__ offsets,
                       unsigned short* __restrict__ xb, unsigned short* __restrict__ Wb) {
    int t = blockIdx.x * 256 + threadIdx.x;          // 2,097,152 threads
    int4 p = ((const int4*)packed)[t];
    int g = t >> 4;
    float s = scales[g], o = offsets[g];
    ushort8 r;
    r[0] = f2bf((float)(p.x & 15) * s + o); r[1] = f2bf((float)((p.x >> 4) & 15) * s + o);
    r[2] = f2bf((float)(p.y & 15) * s + o); r[3] = f2bf((float)((p.y >> 4) & 15) * s + o);
    r[4] = f2bf((float)(p.z & 15) * s + o); r[5] = f2bf((float)((p.z >> 4) & 15) * s + o);
    r[6] = f2bf((float)(p.w & 15) * s + o); r[7] = f2bf((float)((p.w >> 4) & 15) * s + o);
    *(ushort8*)(Wb + 8 * (size_t)t) = r;
    if (t < 524288) {
        const float4* xv = (const float4*)x;
        float4 a = xv[2 * t], b = xv[2 * t + 1];
        ushort8 ox;
        ox[0] = f2bf(a.x); ox[1] = f2bf(a.y); ox[2] = f2bf(a.z); ox[3] = f2bf(a.w);
        ox[4] = f2bf(b.x); ox[5] = f2bf(b.y); ox[6] = f2bf(b.z); ox[7] = f2bf(b.w);
        *(ushort8*)(xb + 8 * (size_t)t) = ox;
    }
}

// ---- outlier scatter, last-write-wins via priority atomicMax ----
__global__ void k_out0(const int* __restrict__ idx, int* __restrict__ maxk, int n) {
    int t = blockIdx.x * 256 + threadIdx.x;
    if (t < n) maxk[idx[t]] = 0;
}
__global__ void k_out1(const int* __restrict__ idx, int* __restrict__ maxk, int n) {
    int t = blockIdx.x * 256 + threadIdx.x;
    if (t < n) atomicMax(&maxk[idx[t]], t + 1);
}
__global__ void k_out2(const int* __restrict__ idx, const float* __restrict__ val,
                       const int* __restrict__ maxk, unsigned short* __restrict__ Wb, int n) {
    int t = blockIdx.x * 256 + threadIdx.x;
    if (t < n) {
        int i = idx[t];
        if (maxk[i] == t + 1) Wb[i] = f2bf(val[t]);
    }
}

// ---- 256x256 tile, BK=64, 8-wave, counted-vmcnt phase-pipelined GEMM ----
// LDS layout: sA[2 buf][2 khalf][256 rows][32 cols] bf16 (16KB units), sB same.
// XOR swizzle: 16B chunk index kc within a row is stored at kc ^ ((row>>1)&3).
// Stage (global_load_lds) writes linearly; the global SOURCE address is
// pre-swizzled; ds_read applies the same XOR. 2 lanes/bank -> conflict-free.
__global__ __launch_bounds__(512, 2)
void k_gemm(const unsigned short* __restrict__ A, const unsigned short* __restrict__ B,
            unsigned short* __restrict__ P) {
    __shared__ __align__(16) char lds[131072];
    char* ldsA = lds;
    char* ldsB = lds + 65536;

    const int tid = threadIdx.x;
    const int wave = tid >> 6, lane = tid & 63;
    const int wr = wave >> 2, wc = wave & 3;        // 2x4 wave grid, 128x64 out each
    const int l15 = lane & 15, l4 = lane >> 4;

    // bijective XCD swizzle (256 blocks, 8 XCDs)
    int s = blockIdx.x;
    int swz = (s & 7) * 32 + (s >> 3);
    const int bn = swz & 15, bm = (swz >> 4) & 3, ks = swz >> 6;

    const unsigned short* Ag = A + (size_t)(bm * 256) * K_DIM + ks * (K_DIM / SPLITK);
    const unsigned short* Bg = B + (size_t)(bn * 256) * K_DIM + ks * (K_DIM / SPLITK);

    // stage-side address precompute (phys offset = j*8192 + tid*16 within a 16KB unit)
    const int srow = tid >> 2;                                   // + j*128
    const int kc8  = ((tid & 3) ^ ((tid >> 3) & 3)) * 8;         // swizzled k-chunk (elems)
    // read-side swizzled byte offsets
    const int kcsw = (l4 ^ ((l15 >> 1) & 3)) << 4;
    const int rdA  = (wr * 128 + l15) * 64 + kcsw;
    const int rdB  = (wc * 64  + l15) * 64 + kcsw;

#define DS_A(c, kh, f) (*(const bf16x8*)(ldsA + (c) * 32768 + (kh) * 16384 + rdA + (f) * 1024))
#define DS_B(c, kh, n) (*(const bf16x8*)(ldsB + (c) * 32768 + (kh) * 16384 + rdB + (n) * 1024))
#define STAGE(XG, ldsX, kt_, kh_, c_) do {                                         \
        int ktc_ = (kt_) < KT_PER ? (kt_) : KT_PER - 1;                            \
        const unsigned short* s0_ = (XG) + (size_t)(srow)       * K_DIM + ktc_ * 64 + (kh_) * 32 + kc8; \
        const unsigned short* s1_ = (XG) + (size_t)(srow + 128) * K_DIM + ktc_ * 64 + (kh_) * 32 + kc8; \
        char* d_ = (ldsX) + (c_) * 32768 + (kh_) * 16384 + wave * 1024;            \
        gload_lds16(s0_, d_);                                                      \
        gload_lds16(s1_, d_ + 8192);                                               \
    } while (0)

    f32x4 acc[8][4] = {};
    bf16x8 af[8];
    bf16x8 b0, b1;

    // prologue: kt0 fully + kt1 k-half0 (6 units = 12 loads)
    STAGE(Ag, ldsA, 0, 0, 0); STAGE(Bg, ldsB, 0, 0, 0);
    STAGE(Ag, ldsA, 0, 1, 0); STAGE(Bg, ldsB, 0, 1, 0);
    STAGE(Ag, ldsA, 1, 0, 1); STAGE(Bg, ldsB, 1, 0, 1);
    asm volatile("s_waitcnt vmcnt(8)" ::: "memory");   // kt0.kh0 (A,B) landed
    __builtin_amdgcn_s_barrier();

    for (int kt = 0; kt < KT_PER; ++kt) {
        const int c = kt & 1;
        // ---- P0: khalf 0, n-half 0 ----
#pragma unroll
        for (int f = 0; f < 8; ++f) af[f] = DS_A(c, 0, f);
        b0 = DS_B(c, 0, 0); b1 = DS_B(c, 0, 1);
        STAGE(Ag, ldsA, kt + 1, 1, c ^ 1);             // region dead since prev iter
        __builtin_amdgcn_s_barrier();
        asm volatile("s_waitcnt lgkmcnt(0)" ::: "memory");
        __builtin_amdgcn_sched_barrier(0);
        __builtin_amdgcn_s_setprio(1);
#pragma unroll
        for (int m = 0; m < 8; ++m) {
            acc[m][0] = MFMA16(af[m], b0, acc[m][0]);
            acc[m][1] = MFMA16(af[m], b1, acc[m][1]);
        }
        __builtin_amdgcn_s_setprio(0);
        __builtin_amdgcn_s_barrier();
        // ---- P1: khalf 0, n-half 1 (A frags reused) ----
        b0 = DS_B(c, 0, 2); b1 = DS_B(c, 0, 3);
        STAGE(Bg, ldsB, kt + 1, 1, c ^ 1);
        asm volatile("s_waitcnt vmcnt(8)" ::: "memory");   // kt.kh1 (A,B) landed
        __builtin_amdgcn_s_barrier();
        asm volatile("s_waitcnt lgkmcnt(0)" ::: "memory");
        __builtin_amdgcn_sched_barrier(0);
        __builtin_amdgcn_s_setprio(1);
#pragma unroll
        for (int m = 0; m < 8; ++m) {
            acc[m][2] = MFMA16(af[m], b0, acc[m][2]);
            acc[m][3] = MFMA16(af[m], b1, acc[m][3]);
        }
        __builtin_amdgcn_s_setprio(0);
        __builtin_amdgcn_s_barrier();
        // ---- P2: khalf 1, n-half 0 ----
#pragma unroll
        for (int f = 0; f < 8; ++f) af[f] = DS_A(c, 1, f);
        b0 = DS_B(c, 1, 0); b1 = DS_B(c, 1, 1);
        STAGE(Ag, ldsA, kt + 2, 0, c);                 // c.kh0 dead after P1
        __builtin_amdgcn_s_barrier();
        asm volatile("s_waitcnt lgkmcnt(0)" ::: "memory");
        __builtin_amdgcn_sched_barrier(0);
        __builtin_amdgcn_s_setprio(1);
#pragma unroll
        for (int m = 0; m < 8; ++m) {
            acc[m][0] = MFMA16(af[m], b0, acc[m][0]);
            acc[m][1] = MFMA16(af[m], b1, acc[m][1]);
        }
        __builtin_amdgcn_s_setprio(0);
        __builtin_amdgcn_s_barrier();
        // ---- P3: khalf 1, n-half 1 ----
        b0 = DS_B(c, 1, 2); b1 = DS_B(c, 1, 3);
        STAGE(Bg, ldsB, kt + 2, 0, c);
        asm volatile("s_waitcnt vmcnt(8)" ::: "memory");   // (kt+1).kh0 (A,B) landed
        __builtin_amdgcn_s_barrier();
        asm volatile("s_waitcnt lgkmcnt(0)" ::: "memory");
        __builtin_amdgcn_sched_barrier(0);
        __builtin_amdgcn_s_setprio(1);
#pragma unroll
        for (int m = 0; m < 8; ++m) {
            acc[m][2] = MFMA16(af[m], b0, acc[m][2]);
            acc[m][3] = MFMA16(af[m], b1, acc[m][3]);
        }
        __builtin_amdgcn_s_setprio(0);
        __builtin_amdgcn_s_barrier();
    }

    // epilogue: bf16 partials
    unsigned short* Pk = P + (size_t)ks * PSZ;
    const int row0 = bm * 256 + wr * 128 + l4 * 4;
    const int col0 = bn * 256 + wc * 64 + l15;
#pragma unroll
    for (int m = 0; m < 8; ++m)
#pragma unroll
        for (int n = 0; n < 4; ++n)
#pragma unroll
            for (int r = 0; r < 4; ++r)
                Pk[(size_t)(row0 + m * 16 + r) * N_DIM + (col0 + n * 16)] = f2bf(acc[m][n][r]);
#undef DS_A
#undef DS_B
#undef STAGE
}

// ---- reduce 4 bf16 partials + bias -> f32 out ----
__global__ void k_reduce(const unsigned short* __restrict__ P, const float* __restrict__ bias,
                         float* __restrict__ out) {
    int t = blockIdx.x * 256 + threadIdx.x;            // 524,288 threads x 8 elems
    ushort8 a = ((const ushort8*)P)[t];
    ushort8 b = ((const ushort8*)(P + (size_t)PSZ))[t];
    ushort8 c = ((const ushort8*)(P + (size_t)2 * PSZ))[t];
    ushort8 d = ((const ushort8*)(P + (size_t)3 * PSZ))[t];
    int col = (t * 8) & (N_DIM - 1);
    float4 bv0 = *(const float4*)(bias + col);
    float4 bv1 = *(const float4*)(bias + col + 4);
    float4 r0, r1;
    r0.x = bf2f(a[0]) + bf2f(b[0]) + bf2f(c[0]) + bf2f(d[0]) + bv0.x;
    r0.y = bf2f(a[1]) + bf2f(b[1]) + bf2f(c[1]) + bf2f(d[1]) + bv0.y;
    r0.z = bf2f(a[2]) + bf2f(b[2]) + bf2f(c[2]) + bf2f(d[2]) + bv0.z;
    r0.w = bf2f(a[3]) + bf2f(b[3]) + bf2f(c[3]) + bf2f(d[3]) + bv0.w;
    r1.x = bf2f(a[4]) + bf2f(b[4]) + bf2f(c[4]) + bf2f(d[4]) + bv1.x;
    r1.y = bf2f(a[5]) + bf2f(b[5]) + bf2f(c[5]) + bf2f(d[5]) + bv1.y;
    r1.z = bf2f(a[6]) + bf2f(b[6]) + bf2f(c[6]) + bf2f(d[6]) + bv1.z;
    r1.w = bf2f(a[7]) + bf2f(b[7]) + bf2f(c[7]) + bf2f(d[7]) + bv1.w;
    ((float4*)out)[2 * t]     = r0;
    ((float4*)out)[2 * t + 1] = r1;
}

extern "C" void kernel_launch(void* const* d_in, const int* in_sizes, int n_in,
                              void* d_out, int out_size, void* d_ws, size_t ws_size,
                              hipStream_t stream) {
    const float* x       = (const float*)d_in[0];
    const int*   packed  = (const int*)d_in[1];
    const float* scales  = (const float*)d_in[2];
    const float* offsets = (const float*)d_in[3];
    const int*   oidx    = (const int*)d_in[4];
    const float* oval    = (const float*)d_in[5];
    const float* bias    = (const float*)d_in[6];
    float* out = (float*)d_out;

    char* ws = (char*)d_ws;
    unsigned short* xb = (unsigned short*)ws;                                  // 8 MB
    unsigned short* Wb = (unsigned short*)(ws + (size_t)8 * 1024 * 1024);      // 32 MB
    unsigned short* P  = (unsigned short*)(ws + (size_t)40 * 1024 * 1024);     // 32 MB (bf16 partials)
    int*          maxk = (int*)P;   // aliases P (64 MB window): used only pre-GEMM

    k_prep<<<2097152 / 256, 256, 0, stream>>>(x, packed, scales, offsets, xb, Wb);
    k_out0<<<(NOUT + 255) / 256, 256, 0, stream>>>(oidx, maxk, NOUT);
    k_out1<<<(NOUT + 255) / 256, 256, 0, stream>>>(oidx, maxk, NOUT);
    k_out2<<<(NOUT + 255) / 256, 256, 0, stream>>>(oidx, oval, maxk, Wb, NOUT);
    k_gemm<<<256, 512, 0, stream>>>(xb, Wb, P);
    k_reduce<<<(PSZ / 8) / 256, 256, 0, stream>>>(P, bias, out);
}